// Round 1
// baseline (1862.217 us; speedup 1.0000x reference)
//
#include <hip/hip_runtime.h>
#include <math.h>

#define NN 30000
#define EE 480000

// ---------------- softplus = logaddexp(x, 0) ----------------
__device__ __forceinline__ float softplus_f(float x) {
    return fmaxf(x, 0.f) + log1pf(expf(-fabsf(x)));
}

// ---------------- edge pass 1: degree + col histogram ----------------
__global__ void edge_pass1(const int* __restrict__ row, const int* __restrict__ col,
                           const float* __restrict__ ew,
                           float* __restrict__ deg, int* __restrict__ counts, int E) {
    int e = blockIdx.x * blockDim.x + threadIdx.x;
    if (e >= E) return;
    atomicAdd(&deg[row[e]], ew[e]);
    atomicAdd(&counts[col[e]], 1);
}

// ---------------- single-block exclusive scan over counts ----------------
__global__ void scan_kernel(const int* __restrict__ counts, int* __restrict__ offs,
                            int* __restrict__ cursor, int N) {
    __shared__ int s[1024];
    int t = threadIdx.x;
    int chunk = (N + 1023) / 1024;
    int beg = t * chunk;
    int end = min(beg + chunk, N);
    int sum = 0;
    for (int i = beg; i < end; ++i) sum += counts[i];
    s[t] = sum;
    __syncthreads();
    // Hillis-Steele inclusive scan
    for (int off = 1; off < 1024; off <<= 1) {
        int v = (t >= off) ? s[t - off] : 0;
        __syncthreads();
        s[t] += v;
        __syncthreads();
    }
    int run = s[t] - sum;  // exclusive base for this chunk
    for (int i = beg; i < end; ++i) {
        offs[i] = run;
        cursor[i] = run;
        run += counts[i];
    }
    if (t == 1023) offs[N] = s[1023];
}

// ---------------- edge pass 2: scatter into CSR-by-col with weights --------
__global__ void edge_pass2(const int* __restrict__ row, const int* __restrict__ col,
                           const float* __restrict__ ew, const float* __restrict__ deg,
                           int* __restrict__ cursor,
                           int* __restrict__ csr_row, float* __restrict__ csr_w, int E) {
    int e = blockIdx.x * blockDim.x + threadIdx.x;
    if (e >= E) return;
    int r = row[e];
    float d = deg[r];
    float wv = (d > 0.f) ? (-ew[e] / d) : 0.f;  // -(2/lmax)*deg_inv*ew, lmax=2
    int pos = atomicAdd(&cursor[col[e]], 1);
    csr_row[pos] = r;
    csr_w[pos] = wv;
}

// ---------------- copy x into concat buffer col [0,128), stride ld ----------
__global__ void copy_x_kernel(const float* __restrict__ x, float* __restrict__ out,
                              int F, int ld, int N) {
    int idx = blockIdx.x * blockDim.x + threadIdx.x;
    int total = N * F;
    if (idx >= total) return;
    int n = idx / F;
    int f = idx - n * F;
    out[(size_t)n * ld + f] = x[idx];
}

// ---------------- SpMV gather: one wave per node ----------------
// Out[n,f] = scale * sum_e w[e]*A[rows[e],f]  - (Sub ? Sub[n,f] : 0)
__global__ __launch_bounds__(256) void lmv_kernel(
        const float* __restrict__ A, float* __restrict__ Out,
        const float* __restrict__ Sub, int ld,
        const int* __restrict__ offs, const int* __restrict__ rows,
        const float* __restrict__ w, float scale, int F, int N) {
    int node = blockIdx.x * 4 + (threadIdx.x >> 6);
    int lane = threadIdx.x & 63;
    if (node >= N) return;
    int e0 = offs[node], e1 = offs[node + 1];
    int nc = (F + 63) >> 6;
    float acc[8];
    #pragma unroll
    for (int c = 0; c < 8; ++c) acc[c] = 0.f;
    for (int e = e0; e < e1; ++e) {
        int r = rows[e];
        float we = w[e];
        const float* ar = A + (size_t)r * ld;
        for (int c = 0; c < nc; ++c) {
            int f = c * 64 + lane;
            if (f < F) acc[c] += we * ar[f];
        }
    }
    float* orow = Out + (size_t)node * ld;
    if (Sub) {
        const float* srow = Sub + (size_t)node * ld;
        for (int c = 0; c < nc; ++c) {
            int f = c * 64 + lane;
            if (f < F) orow[f] = scale * acc[c] - srow[f];
        }
    } else {
        for (int c = 0; c < nc; ++c) {
            int f = c * 64 + lane;
            if (f < F) orow[f] = acc[c];
        }
    }
}

// ---------------- fp32 tiled GEMM + bias + softplus ----------------
// Out[m, n] = softplus( sum_k A[m,k]*B[k,n] + bias[n] ), Out has stride ldo.
// A: (M, K) stride lda; B: (K, Ncols) stride ldb. K % 16 == 0, Ncols % 16 == 0.
__global__ __launch_bounds__(256) void gemm_softplus(
        const float* __restrict__ A, int lda, int M, int K,
        const float* __restrict__ B, int ldb, int Ncols,
        const float* __restrict__ bias,
        float* __restrict__ Out, int ldo) {
    __shared__ float As[16][64 + 4];
    __shared__ float Bs[16][64 + 4];
    int tid = threadIdx.x;
    int tx = tid & 15, ty = tid >> 4;
    int row0 = blockIdx.x * 64;
    int col0 = blockIdx.y * 64;
    float acc[4][4];
    #pragma unroll
    for (int i = 0; i < 4; ++i)
        #pragma unroll
        for (int j = 0; j < 4; ++j) acc[i][j] = 0.f;

    for (int k0 = 0; k0 < K; k0 += 16) {
        // load A tile: 64 rows x 16 k; each thread a float4
        {
            int r = tid >> 2;
            int kq = (tid & 3) * 4;
            int gr = row0 + r;
            float4 v = make_float4(0.f, 0.f, 0.f, 0.f);
            if (gr < M) v = *(const float4*)(A + (size_t)gr * lda + k0 + kq);
            As[kq + 0][r] = v.x;
            As[kq + 1][r] = v.y;
            As[kq + 2][r] = v.z;
            As[kq + 3][r] = v.w;
        }
        // load B tile: 16 k x 64 cols; each thread a float4
        {
            int kk = tid >> 4;
            int n4 = (tid & 15) * 4;
            int gc = col0 + n4;
            float4 v = make_float4(0.f, 0.f, 0.f, 0.f);
            if (gc < Ncols) v = *(const float4*)(B + (size_t)(k0 + kk) * ldb + gc);
            Bs[kk][n4 + 0] = v.x;
            Bs[kk][n4 + 1] = v.y;
            Bs[kk][n4 + 2] = v.z;
            Bs[kk][n4 + 3] = v.w;
        }
        __syncthreads();
        #pragma unroll
        for (int kk = 0; kk < 16; ++kk) {
            float a[4], b[4];
            #pragma unroll
            for (int i = 0; i < 4; ++i) a[i] = As[kk][ty * 4 + i];
            #pragma unroll
            for (int j = 0; j < 4; ++j) b[j] = Bs[kk][tx * 4 + j];
            #pragma unroll
            for (int i = 0; i < 4; ++i)
                #pragma unroll
                for (int j = 0; j < 4; ++j) acc[i][j] += a[i] * b[j];
        }
        __syncthreads();
    }
    // epilogue: bias + softplus
    #pragma unroll
    for (int i = 0; i < 4; ++i) {
        int m = row0 + ty * 4 + i;
        if (m >= M) continue;
        #pragma unroll
        for (int j = 0; j < 4; ++j) {
            int n = col0 + tx * 4 + j;
            if (n >= Ncols) continue;
            float v = acc[i][j] + bias[n];
            Out[(size_t)m * ldo + n] = softplus_f(v);
        }
    }
}

// ---------------- final FC: (N,512) @ (512,3) + b, one wave per row --------
__global__ __launch_bounds__(256) void fc_kernel(
        const float* __restrict__ H, const float* __restrict__ Wfc,
        const float* __restrict__ bfc, float* __restrict__ Out, int M) {
    int wave = blockIdx.x * 4 + (threadIdx.x >> 6);
    int lane = threadIdx.x & 63;
    if (wave >= M) return;
    const float* h = H + (size_t)wave * 512;
    float a0 = 0.f, a1 = 0.f, a2 = 0.f;
    #pragma unroll
    for (int it = 0; it < 8; ++it) {
        int k = it * 64 + lane;
        float x = h[k];
        a0 += x * Wfc[k * 3 + 0];
        a1 += x * Wfc[k * 3 + 1];
        a2 += x * Wfc[k * 3 + 2];
    }
    #pragma unroll
    for (int off = 32; off > 0; off >>= 1) {
        a0 += __shfl_down(a0, off);
        a1 += __shfl_down(a1, off);
        a2 += __shfl_down(a2, off);
    }
    if (lane == 0) {
        Out[wave * 3 + 0] = a0 + bfc[0];
        Out[wave * 3 + 1] = a1 + bfc[1];
        Out[wave * 3 + 2] = a2 + bfc[2];
    }
}

static inline size_t align256(size_t x) { return (x + 255) & ~(size_t)255; }

extern "C" void kernel_launch(void* const* d_in, const int* in_sizes, int n_in,
                              void* d_out, int out_size, void* d_ws, size_t ws_size,
                              hipStream_t stream) {
    const float* x   = (const float*)d_in[0];
    const int*   ei  = (const int*)d_in[1];
    const float* ew  = (const float*)d_in[2];
    // d_in[3] = batch (identity pooling; unused)
    const float* W[6]  = { (const float*)d_in[4],  (const float*)d_in[6],
                           (const float*)d_in[8],  (const float*)d_in[10],
                           (const float*)d_in[12], (const float*)d_in[14] };
    const float* Bv[6] = { (const float*)d_in[5],  (const float*)d_in[7],
                           (const float*)d_in[9],  (const float*)d_in[11],
                           (const float*)d_in[13], (const float*)d_in[15] };
    const float* fc_w = (const float*)d_in[16];
    const float* fc_b = (const float*)d_in[17];
    float* out = (float*)d_out;

    const int* e_row = ei;        // edge_index[0]
    const int* e_col = ei + EE;   // edge_index[1]

    // ---- workspace carve ----
    char* p = (char*)d_ws;
    float* deg    = (float*)p; p += align256((size_t)NN * 4);
    int*   counts = (int*)p;   p += align256((size_t)NN * 4);
    int*   offs   = (int*)p;   p += align256((size_t)(NN + 1) * 4);
    int*   cursor = (int*)p;   p += align256((size_t)NN * 4);
    int*   csr_r  = (int*)p;   p += align256((size_t)EE * 4);
    float* csr_w  = (float*)p; p += align256((size_t)EE * 4);
    float* buf0   = (float*)p; p += align256((size_t)NN * 512 * 4);
    float* buf1   = (float*)p; p += align256((size_t)NN * 768 * 4);
    (void)ws_size; (void)n_in; (void)in_sizes; (void)out_size;

    // ---- graph preprocessing ----
    hipMemsetAsync(deg, 0, (size_t)NN * 4, stream);
    hipMemsetAsync(counts, 0, (size_t)NN * 4, stream);
    {
        int blocks = (EE + 255) / 256;
        edge_pass1<<<blocks, 256, 0, stream>>>(e_row, e_col, ew, deg, counts, EE);
        scan_kernel<<<1, 1024, 0, stream>>>(counts, offs, cursor, NN);
        edge_pass2<<<blocks, 256, 0, stream>>>(e_row, e_col, ew, deg, cursor, csr_r, csr_w, EE);
    }

    // ---- layer schedule ----
    // L: fi, fo, Abuf, Obuf, ldA(=3*fi), ldO(=3*fo for next concat; L6 -> 512 plain)
    const int fi_arr[6]  = { 128, 16, 32, 64, 128, 256 };
    const int fo_arr[6]  = { 16, 32, 64, 128, 256, 512 };
    float* Abuf[6] = { buf0, buf1, buf0, buf1, buf0, buf1 };
    float* Obuf[6] = { buf1, buf0, buf1, buf0, buf1, buf0 };
    const int ldO_arr[6] = { 48, 96, 192, 384, 768, 512 };  // L6 writes plain (N,512)

    // stage x into buf0 concat slot [0,128), stride 384
    {
        int total = NN * 128;
        copy_x_kernel<<<(total + 255) / 256, 256, 0, stream>>>(x, buf0, 128, 384, NN);
    }

    for (int L = 0; L < 6; ++L) {
        int fi = fi_arr[L], fo = fo_arr[L];
        int ldA = 3 * fi;
        int ldO = ldO_arr[L];
        float* A = Abuf[L];
        float* O = Obuf[L];
        int lmv_blocks = (NN + 3) / 4;
        // Tx1 = Lhat @ Tx0   (cols [fi, 2fi))
        lmv_kernel<<<lmv_blocks, 256, 0, stream>>>(
            A, A + fi, nullptr, ldA, offs, csr_r, csr_w, 1.0f, fi, NN);
        // Tx2 = 2*Lhat @ Tx1 - Tx0   (cols [2fi, 3fi))
        lmv_kernel<<<lmv_blocks, 256, 0, stream>>>(
            A + fi, A + 2 * fi, A, ldA, offs, csr_r, csr_w, 2.0f, fi, NN);
        // Out = softplus([Tx0|Tx1|Tx2] @ W + b) -> next concat slot (cols [0,fo))
        dim3 grid((NN + 63) / 64, (fo + 63) / 64);
        gemm_softplus<<<grid, 256, 0, stream>>>(
            A, ldA, NN, 3 * fi, W[L], fo, fo, Bv[L], O, ldO);
    }

    // final FC: buf0 (N,512) @ fc_w (512,3) + fc_b
    fc_kernel<<<(NN + 3) / 4, 256, 0, stream>>>(buf0, fc_w, fc_b, out, NN);
}

// Round 2
// 969.349 us; speedup vs baseline: 1.9211x; 1.9211x over previous
//
#include <hip/hip_runtime.h>
#include <math.h>

#define NN 30000
#define EE 480000
#define MPAD 30080   // 235 * 128

typedef __attribute__((ext_vector_type(8))) short short8;
typedef __attribute__((ext_vector_type(4))) float floatx4;

// ---------------- bf16 helpers ----------------
__device__ __forceinline__ float b2f(ushort u) {
    union { uint u; float f; } c; c.u = ((uint)u) << 16; return c.f;
}
__device__ __forceinline__ ushort f2b(float f) {
    union { float f; uint u; } c; c.f = f;
    uint u = c.u;
    uint r = (u + 0x7FFFu + ((u >> 16) & 1u)) >> 16;
    return (ushort)r;
}
__device__ __forceinline__ float softplus_f(float x) {
    return fmaxf(x, 0.f) + log1pf(expf(-fabsf(x)));
}

// ---------------- edge pass 1: degree + col histogram ----------------
__global__ void edge_pass1(const int* __restrict__ row, const int* __restrict__ col,
                           const float* __restrict__ ew,
                           float* __restrict__ deg, int* __restrict__ counts, int E) {
    int e = blockIdx.x * blockDim.x + threadIdx.x;
    if (e >= E) return;
    atomicAdd(&deg[row[e]], ew[e]);
    atomicAdd(&counts[col[e]], 1);
}

// ---------------- single-block exclusive scan over counts ----------------
__global__ void scan_kernel(const int* __restrict__ counts, int* __restrict__ offs,
                            int* __restrict__ cursor, int N) {
    __shared__ int s[1024];
    int t = threadIdx.x;
    int chunk = (N + 1023) / 1024;
    int beg = t * chunk;
    int end = min(beg + chunk, N);
    int sum = 0;
    for (int i = beg; i < end; ++i) sum += counts[i];
    s[t] = sum;
    __syncthreads();
    for (int off = 1; off < 1024; off <<= 1) {
        int v = (t >= off) ? s[t - off] : 0;
        __syncthreads();
        s[t] += v;
        __syncthreads();
    }
    int run = s[t] - sum;
    for (int i = beg; i < end; ++i) {
        offs[i] = run;
        cursor[i] = run;
        run += counts[i];
    }
    if (t == 1023) offs[N] = s[1023];
}

// ---------------- edge pass 2: scatter into CSR-by-col ----------------
__global__ void edge_pass2(const int* __restrict__ row, const int* __restrict__ col,
                           const float* __restrict__ ew, const float* __restrict__ deg,
                           int* __restrict__ cursor,
                           int* __restrict__ csr_row, float* __restrict__ csr_w, int E) {
    int e = blockIdx.x * blockDim.x + threadIdx.x;
    if (e >= E) return;
    int r = row[e];
    float d = deg[r];
    float wv = (d > 0.f) ? (-ew[e] / d) : 0.f;  // -(2/lmax)*deg_inv*ew, lmax=2
    int pos = atomicAdd(&cursor[col[e]], 1);
    csr_row[pos] = r;
    csr_w[pos] = wv;
}

// ---------------- copy x (fp32) into bf16 concat buffer ----------------
__global__ void copy_x_kernel(const float* __restrict__ x, ushort* __restrict__ out,
                              int F, int ld, int N) {
    int idx = blockIdx.x * blockDim.x + threadIdx.x;
    int total = N * F;
    if (idx >= total) return;
    int n = idx / F;
    int f = idx - n * F;
    out[(size_t)n * ld + f] = f2b(x[idx]);
}

// ---------------- weight convert + transpose: W (K, fo) fp32 -> Bt (fo, Kpad) bf16
__global__ void wconv_kernel(const float* __restrict__ W, ushort* __restrict__ Bt,
                             int K, int Kpad, int fo) {
    int idx = blockIdx.x * blockDim.x + threadIdx.x;
    int total = fo * Kpad;
    if (idx >= total) return;
    int n = idx / Kpad, k = idx - n * Kpad;
    float v = (k < K) ? W[(size_t)k * fo + n] : 0.f;
    Bt[idx] = f2b(v);
}

// ---------------- SpMV gather (bf16 in/out, fp32 accum) ----------------
// Out[n,:] = scale * sum_e w[e]*A[rows[e],:]  - (Sub ? Sub[n,:] : 0)
// Pointers pre-offset to the column slot; ld in elements.
template <int FI>
__global__ __launch_bounds__(256) void lmv_bf16(
        const ushort* __restrict__ A, ushort* __restrict__ Out,
        const ushort* __restrict__ Sub, int ld,
        const int* __restrict__ offs, const int* __restrict__ rows,
        const float* __restrict__ w, float scale, int N) {
    constexpr int NPW = (FI >= 64) ? 1 : (64 / FI);
    constexpr int VEC = (FI >= 64) ? (FI / 64) : 1;
    int wave = threadIdx.x >> 6;
    int lane = threadIdx.x & 63;
    int sub = (NPW == 1) ? 0 : (lane / FI);
    int fbase = (NPW == 1) ? lane * VEC : (lane & (FI - 1));
    int node = blockIdx.x * (4 * NPW) + wave * NPW + sub;
    if (node >= N) return;
    int e0 = offs[node], e1 = offs[node + 1];
    float acc[VEC];
    #pragma unroll
    for (int v = 0; v < VEC; ++v) acc[v] = 0.f;
    for (int e = e0; e < e1; ++e) {
        int r = rows[e];
        float we = w[e];
        const ushort* p = A + (size_t)r * ld + fbase;
        if constexpr (VEC == 4) {
            ushort4 u = *(const ushort4*)p;
            acc[0] += we * b2f(u.x); acc[1] += we * b2f(u.y);
            acc[2] += we * b2f(u.z); acc[3] += we * b2f(u.w);
        } else if constexpr (VEC == 2) {
            ushort2 u = *(const ushort2*)p;
            acc[0] += we * b2f(u.x); acc[1] += we * b2f(u.y);
        } else {
            acc[0] += we * b2f(*p);
        }
    }
    ushort* o = Out + (size_t)node * ld + fbase;
    if (Sub) {
        const ushort* s = Sub + (size_t)node * ld + fbase;
        #pragma unroll
        for (int v = 0; v < VEC; ++v) o[v] = f2b(scale * acc[v] - b2f(s[v]));
    } else {
        #pragma unroll
        for (int v = 0; v < VEC; ++v) o[v] = f2b(acc[v]);
    }
}

// ---------------- MFMA GEMM + bias + softplus, bf16 in/out ----------------
// A: (MPAD, lda) bf16 row-major; Bt: (fo, K) bf16 row-major (pre-transposed);
// Out: (MPAD, ldo) bf16. K % 32 == 0. No M/N guards (M padded, N = grid*BN).
template <int BN>
__global__ __launch_bounds__(256) void gemm_mfma(
        const ushort* __restrict__ A, int lda, int K,
        const ushort* __restrict__ Bt,
        const float* __restrict__ bias,
        ushort* __restrict__ Out, int ldo) {
    constexpr int BM = 128, BK = 32;
    constexpr int WR = (BN == 128) ? 2 : 4;   // waves along M
    constexpr int SM = BM / WR;               // wave M-span: 64 or 32
    constexpr int SN = (BN == 128) ? 64 : BN; // wave N-span
    constexpr int FM = SM / 16;
    constexpr int FN = SN / 16;
    __shared__ ushort As[BM][BK + 8];
    __shared__ ushort Bs[BN][BK + 8];
    int tid = threadIdx.x;
    int wv = tid >> 6, lane = tid & 63;
    int wm = (BN == 128) ? (wv & 1) : wv;
    int wn = (BN == 128) ? (wv >> 1) : 0;
    int q = lane >> 4, r16 = lane & 15;
    int m0 = blockIdx.x * BM;
    int n0 = blockIdx.y * BN;

    floatx4 acc[FM][FN];
    #pragma unroll
    for (int i = 0; i < FM; ++i)
        #pragma unroll
        for (int j = 0; j < FN; ++j) acc[i][j] = (floatx4){0.f, 0.f, 0.f, 0.f};

    for (int k0 = 0; k0 < K; k0 += BK) {
        // stage A tile: 128 x 32 bf16, 16B per thread-segment
        #pragma unroll
        for (int i = 0; i < 2; ++i) {
            int idx = tid + i * 256;
            int row = idx >> 2, seg = idx & 3;
            *(short8*)&As[row][seg * 8] =
                *(const short8*)(A + (size_t)(m0 + row) * lda + k0 + seg * 8);
        }
        // stage B tile: BN x 32 bf16
        for (int idx = tid; idx < BN * 4; idx += 256) {
            int row = idx >> 2, seg = idx & 3;
            *(short8*)&Bs[row][seg * 8] =
                *(const short8*)(Bt + (size_t)(n0 + row) * K + k0 + seg * 8);
        }
        __syncthreads();
        short8 af[FM], bf[FN];
        #pragma unroll
        for (int i = 0; i < FM; ++i)
            af[i] = *(const short8*)&As[wm * SM + i * 16 + r16][q * 8];
        #pragma unroll
        for (int j = 0; j < FN; ++j)
            bf[j] = *(const short8*)&Bs[wn * SN + j * 16 + r16][q * 8];
        #pragma unroll
        for (int i = 0; i < FM; ++i)
            #pragma unroll
            for (int j = 0; j < FN; ++j)
                acc[i][j] = __builtin_amdgcn_mfma_f32_16x16x32_bf16(
                    af[i], bf[j], acc[i][j], 0, 0, 0);
        __syncthreads();
    }
    // epilogue: bias + softplus -> bf16
    #pragma unroll
    for (int i = 0; i < FM; ++i) {
        #pragma unroll
        for (int j = 0; j < FN; ++j) {
            int n = n0 + wn * SN + j * 16 + r16;
            float bv = bias[n];
            #pragma unroll
            for (int r = 0; r < 4; ++r) {
                int m = m0 + wm * SM + i * 16 + q * 4 + r;
                float v = acc[i][j][r] + bv;
                Out[(size_t)m * ldo + n] = f2b(softplus_f(v));
            }
        }
    }
}

// ---------------- final FC: (N,512) bf16 @ (512,3) fp32 + b ----------------
__global__ __launch_bounds__(256) void fc_kernel(
        const ushort* __restrict__ H, const float* __restrict__ Wfc,
        const float* __restrict__ bfc, float* __restrict__ Out, int M) {
    int node = blockIdx.x * 4 + (threadIdx.x >> 6);
    int lane = threadIdx.x & 63;
    if (node >= M) return;
    const ushort* h = H + (size_t)node * 512 + lane * 8;
    ushort4 v0 = *(const ushort4*)h;
    ushort4 v1 = *(const ushort4*)(h + 4);
    ushort vv[8] = {v0.x, v0.y, v0.z, v0.w, v1.x, v1.y, v1.z, v1.w};
    float a0 = 0.f, a1 = 0.f, a2 = 0.f;
    #pragma unroll
    for (int j = 0; j < 8; ++j) {
        float x = b2f(vv[j]);
        int k = lane * 8 + j;
        a0 += x * Wfc[k * 3 + 0];
        a1 += x * Wfc[k * 3 + 1];
        a2 += x * Wfc[k * 3 + 2];
    }
    #pragma unroll
    for (int off = 32; off > 0; off >>= 1) {
        a0 += __shfl_down(a0, off);
        a1 += __shfl_down(a1, off);
        a2 += __shfl_down(a2, off);
    }
    if (lane == 0) {
        Out[node * 3 + 0] = a0 + bfc[0];
        Out[node * 3 + 1] = a1 + bfc[1];
        Out[node * 3 + 2] = a2 + bfc[2];
    }
}

static inline size_t align256(size_t x) { return (x + 255) & ~(size_t)255; }

extern "C" void kernel_launch(void* const* d_in, const int* in_sizes, int n_in,
                              void* d_out, int out_size, void* d_ws, size_t ws_size,
                              hipStream_t stream) {
    const float* x   = (const float*)d_in[0];
    const int*   ei  = (const int*)d_in[1];
    const float* ew  = (const float*)d_in[2];
    const float* W[6]  = { (const float*)d_in[4],  (const float*)d_in[6],
                           (const float*)d_in[8],  (const float*)d_in[10],
                           (const float*)d_in[12], (const float*)d_in[14] };
    const float* Bv[6] = { (const float*)d_in[5],  (const float*)d_in[7],
                           (const float*)d_in[9],  (const float*)d_in[11],
                           (const float*)d_in[13], (const float*)d_in[15] };
    const float* fc_w = (const float*)d_in[16];
    const float* fc_b = (const float*)d_in[17];
    float* out = (float*)d_out;

    const int* e_row = ei;        // edge_index[0]
    const int* e_col = ei + EE;   // edge_index[1]

    const int fi_arr[6]   = { 128, 16, 32, 64, 128, 256 };
    const int fo_arr[6]   = { 16, 32, 64, 128, 256, 512 };
    const int Kpad_arr[6] = { 384, 64, 96, 192, 384, 768 };  // K rounded to 32
    const int ldo_arr[6]  = { 64, 96, 192, 384, 768, 512 };  // next layer's Kpad; L6 plain

    // ---- workspace carve ----
    char* p = (char*)d_ws;
    float* deg    = (float*)p; p += align256((size_t)NN * 4);
    int*   counts = (int*)p;   p += align256((size_t)NN * 4);
    int*   offs   = (int*)p;   p += align256((size_t)(NN + 1) * 4);
    int*   cursor = (int*)p;   p += align256((size_t)NN * 4);
    int*   csr_r  = (int*)p;   p += align256((size_t)EE * 4);
    float* csr_w  = (float*)p; p += align256((size_t)EE * 4);
    ushort* Bt[6];
    for (int L = 0; L < 6; ++L) {
        Bt[L] = (ushort*)p;
        p += align256((size_t)fo_arr[L] * Kpad_arr[L] * 2);
    }
    ushort* buf0 = (ushort*)p; p += align256((size_t)MPAD * 768 * 2);
    ushort* buf1 = (ushort*)p; p += align256((size_t)MPAD * 768 * 2);
    (void)ws_size; (void)n_in; (void)in_sizes; (void)out_size;

    // ---- zero init (ws is poisoned 0xAA before every call) ----
    hipMemsetAsync(deg, 0, (size_t)NN * 4, stream);
    hipMemsetAsync(counts, 0, (size_t)NN * 4, stream);
    hipMemsetAsync(buf0, 0, (size_t)MPAD * 768 * 2, stream);
    hipMemsetAsync(buf1, 0, (size_t)MPAD * 768 * 2, stream);

    // ---- graph preprocessing ----
    {
        int blocks = (EE + 255) / 256;
        edge_pass1<<<blocks, 256, 0, stream>>>(e_row, e_col, ew, deg, counts, EE);
        scan_kernel<<<1, 1024, 0, stream>>>(counts, offs, cursor, NN);
        edge_pass2<<<blocks, 256, 0, stream>>>(e_row, e_col, ew, deg, cursor, csr_r, csr_w, EE);
    }

    // ---- weights -> bf16 transposed (fo, Kpad) ----
    for (int L = 0; L < 6; ++L) {
        int total = fo_arr[L] * Kpad_arr[L];
        wconv_kernel<<<(total + 255) / 256, 256, 0, stream>>>(
            W[L], Bt[L], 3 * fi_arr[L], Kpad_arr[L], fo_arr[L]);
    }

    // ---- stage x into buf0 cols [0,128), ld=384, bf16 ----
    {
        int total = NN * 128;
        copy_x_kernel<<<(total + 255) / 256, 256, 0, stream>>>(x, buf0, 128, 384, NN);
    }

    ushort* Abuf[6] = { buf0, buf1, buf0, buf1, buf0, buf1 };
    ushort* Obuf[6] = { buf1, buf0, buf1, buf0, buf1, buf0 };

    for (int L = 0; L < 6; ++L) {
        int fi = fi_arr[L], fo = fo_arr[L];
        int ldA = Kpad_arr[L];
        int ldO = ldo_arr[L];
        ushort* A = Abuf[L];
        ushort* O = Obuf[L];

        // two SpMV passes: Tx1 = Lhat@Tx0; Tx2 = 2*Lhat@Tx1 - Tx0
        #define LMV_LAUNCH(FI, NB)                                                     \
            lmv_bf16<FI><<<NB, 256, 0, stream>>>(A, A + fi, nullptr, ldA,              \
                                                 offs, csr_r, csr_w, 1.0f, NN);        \
            lmv_bf16<FI><<<NB, 256, 0, stream>>>(A + fi, A + 2 * fi, A, ldA,           \
                                                 offs, csr_r, csr_w, 2.0f, NN);
        switch (fi) {
            case 16:  { LMV_LAUNCH(16,  (NN + 15) / 16) } break;
            case 32:  { LMV_LAUNCH(32,  (NN + 7) / 8) } break;
            case 64:  { LMV_LAUNCH(64,  (NN + 3) / 4) } break;
            case 128: { LMV_LAUNCH(128, (NN + 3) / 4) } break;
            case 256: { LMV_LAUNCH(256, (NN + 3) / 4) } break;
        }
        #undef LMV_LAUNCH

        // GEMM: Out = softplus([Tx0|Tx1|Tx2] @ W + b)
        int K = Kpad_arr[L];
        dim3 grid(MPAD / 128, (fo + 127) / 128);
        switch (fo) {
            case 16:
                gemm_mfma<16><<<dim3(MPAD / 128, 1), 256, 0, stream>>>(
                    A, ldA, K, Bt[L], Bv[L], O, ldO);
                break;
            case 32:
                gemm_mfma<32><<<dim3(MPAD / 128, 1), 256, 0, stream>>>(
                    A, ldA, K, Bt[L], Bv[L], O, ldO);
                break;
            case 64:
                gemm_mfma<64><<<dim3(MPAD / 128, 1), 256, 0, stream>>>(
                    A, ldA, K, Bt[L], Bv[L], O, ldO);
                break;
            default:
                gemm_mfma<128><<<dim3(MPAD / 128, fo / 128), 256, 0, stream>>>(
                    A, ldA, K, Bt[L], Bv[L], O, ldO);
                break;
        }
    }

    // final FC: buf0 (N,512) bf16 @ fc_w (512,3) + fc_b
    fc_kernel<<<(NN + 3) / 4, 256, 0, stream>>>(buf0, fc_w, fc_b, out, NN);
}

// Round 3
// 772.200 us; speedup vs baseline: 2.4116x; 1.2553x over previous
//
#include <hip/hip_runtime.h>
#include <math.h>
#include <stdint.h>

#define NN 30000
#define EE 480000
#define MPAD 30080   // 235 * 128

typedef __attribute__((ext_vector_type(8))) short short8;
typedef __attribute__((ext_vector_type(4))) float floatx4;

// ---------------- bf16 helpers ----------------
__device__ __forceinline__ float b2f(ushort u) {
    union { uint u; float f; } c; c.u = ((uint)u) << 16; return c.f;
}
__device__ __forceinline__ ushort f2b(float f) {
    union { float f; uint u; } c; c.f = f;
    uint u = c.u;
    uint r = (u + 0x7FFFu + ((u >> 16) & 1u)) >> 16;
    return (ushort)r;
}
__device__ __forceinline__ float softplus_f(float x) {
    return fmaxf(x, 0.f) + log1pf(expf(-fabsf(x)));
}

// ---- async global->LDS, 16B per lane. LDS dest = wave-uniform base + lane*16.
__device__ __forceinline__ void gld_lds16(const void* g, void* lds) {
    __builtin_amdgcn_global_load_lds(
        (__attribute__((address_space(1))) void*)(uintptr_t)(g),
        (__attribute__((address_space(3))) void*)(uint32_t)(uintptr_t)(lds),
        16, 0, 0);
}

// ---------------- edge pass 1: degree + col histogram ----------------
__global__ void edge_pass1(const int* __restrict__ row, const int* __restrict__ col,
                           const float* __restrict__ ew,
                           float* __restrict__ deg, int* __restrict__ counts, int E) {
    int e = blockIdx.x * blockDim.x + threadIdx.x;
    if (e >= E) return;
    atomicAdd(&deg[row[e]], ew[e]);
    atomicAdd(&counts[col[e]], 1);
}

// ---------------- single-block exclusive scan over counts ----------------
__global__ void scan_kernel(const int* __restrict__ counts, int* __restrict__ offs,
                            int* __restrict__ cursor, int N) {
    __shared__ int s[1024];
    int t = threadIdx.x;
    int chunk = (N + 1023) / 1024;
    int beg = t * chunk;
    int end = min(beg + chunk, N);
    int sum = 0;
    for (int i = beg; i < end; ++i) sum += counts[i];
    s[t] = sum;
    __syncthreads();
    for (int off = 1; off < 1024; off <<= 1) {
        int v = (t >= off) ? s[t - off] : 0;
        __syncthreads();
        s[t] += v;
        __syncthreads();
    }
    int run = s[t] - sum;
    for (int i = beg; i < end; ++i) {
        offs[i] = run;
        cursor[i] = run;
        run += counts[i];
    }
    if (t == 1023) offs[N] = s[1023];
}

// ---------------- edge pass 2: scatter into CSR-by-col ----------------
__global__ void edge_pass2(const int* __restrict__ row, const int* __restrict__ col,
                           const float* __restrict__ ew, const float* __restrict__ deg,
                           int* __restrict__ cursor,
                           int* __restrict__ csr_row, float* __restrict__ csr_w, int E) {
    int e = blockIdx.x * blockDim.x + threadIdx.x;
    if (e >= E) return;
    int r = row[e];
    float d = deg[r];
    float wv = (d > 0.f) ? (-ew[e] / d) : 0.f;  // -(2/lmax)*deg_inv*ew, lmax=2
    int pos = atomicAdd(&cursor[col[e]], 1);
    csr_row[pos] = r;
    csr_w[pos] = wv;
}

// ---------------- copy x (fp32) into bf16 concat buffer ----------------
__global__ void copy_x_kernel(const float* __restrict__ x, ushort* __restrict__ out,
                              int F, int ld, int N) {
    int idx = blockIdx.x * blockDim.x + threadIdx.x;
    int total = N * F;
    if (idx >= total) return;
    int n = idx / F;
    int f = idx - n * F;
    out[(size_t)n * ld + f] = f2b(x[idx]);
}

// ---------------- weight convert + transpose: W (K, fo) fp32 -> Bt (fo, Kpad) bf16
__global__ void wconv_kernel(const float* __restrict__ W, ushort* __restrict__ Bt,
                             int K, int Kpad, int fo) {
    int idx = blockIdx.x * blockDim.x + threadIdx.x;
    int total = fo * Kpad;
    if (idx >= total) return;
    int n = idx / Kpad, k = idx - n * Kpad;
    float v = (k < K) ? W[(size_t)k * fo + n] : 0.f;
    Bt[idx] = f2b(v);
}

// ---------------- SpMV gather (bf16 in/out, fp32 accum, 2 MLP chains) -------
template <int FI>
__global__ __launch_bounds__(256) void lmv_bf16(
        const ushort* __restrict__ A, ushort* __restrict__ Out,
        const ushort* __restrict__ Sub, int ld,
        const int* __restrict__ offs, const int* __restrict__ rows,
        const float* __restrict__ w, float scale, int N) {
    constexpr int NPW = (FI >= 64) ? 1 : (64 / FI);
    constexpr int VEC = (FI >= 64) ? (FI / 64) : 1;
    int wave = threadIdx.x >> 6;
    int lane = threadIdx.x & 63;
    int sub = (NPW == 1) ? 0 : (lane / FI);
    int fbase = (NPW == 1) ? lane * VEC : (lane & (FI - 1));
    int node = blockIdx.x * (4 * NPW) + wave * NPW + sub;
    if (node >= N) return;
    int e0 = offs[node], e1 = offs[node + 1];
    float acc0[VEC], acc1[VEC];
    #pragma unroll
    for (int v = 0; v < VEC; ++v) { acc0[v] = 0.f; acc1[v] = 0.f; }
    int e = e0;
    for (; e + 2 <= e1; e += 2) {
        int ra = rows[e], rb = rows[e + 1];
        float wa = w[e], wb = w[e + 1];
        const ushort* pa = A + (size_t)ra * ld + fbase;
        const ushort* pb = A + (size_t)rb * ld + fbase;
        if constexpr (VEC == 4) {
            ushort4 ua = *(const ushort4*)pa;
            ushort4 ub = *(const ushort4*)pb;
            acc0[0] += wa * b2f(ua.x); acc0[1] += wa * b2f(ua.y);
            acc0[2] += wa * b2f(ua.z); acc0[3] += wa * b2f(ua.w);
            acc1[0] += wb * b2f(ub.x); acc1[1] += wb * b2f(ub.y);
            acc1[2] += wb * b2f(ub.z); acc1[3] += wb * b2f(ub.w);
        } else if constexpr (VEC == 2) {
            ushort2 ua = *(const ushort2*)pa;
            ushort2 ub = *(const ushort2*)pb;
            acc0[0] += wa * b2f(ua.x); acc0[1] += wa * b2f(ua.y);
            acc1[0] += wb * b2f(ub.x); acc1[1] += wb * b2f(ub.y);
        } else {
            acc0[0] += wa * b2f(*pa);
            acc1[0] += wb * b2f(*pb);
        }
    }
    if (e < e1) {
        int ra = rows[e];
        float wa = w[e];
        const ushort* pa = A + (size_t)ra * ld + fbase;
        if constexpr (VEC == 4) {
            ushort4 ua = *(const ushort4*)pa;
            acc0[0] += wa * b2f(ua.x); acc0[1] += wa * b2f(ua.y);
            acc0[2] += wa * b2f(ua.z); acc0[3] += wa * b2f(ua.w);
        } else if constexpr (VEC == 2) {
            ushort2 ua = *(const ushort2*)pa;
            acc0[0] += wa * b2f(ua.x); acc0[1] += wa * b2f(ua.y);
        } else {
            acc0[0] += wa * b2f(*pa);
        }
    }
    ushort* o = Out + (size_t)node * ld + fbase;
    if (Sub) {
        const ushort* s = Sub + (size_t)node * ld + fbase;
        #pragma unroll
        for (int v = 0; v < VEC; ++v)
            o[v] = f2b(scale * (acc0[v] + acc1[v]) - b2f(s[v]));
    } else {
        #pragma unroll
        for (int v = 0; v < VEC; ++v) o[v] = f2b(acc0[v] + acc1[v]);
    }
}

// ---------------- MFMA GEMM, global_load_lds staging, bias+softplus ---------
// A: (MPAD, lda) bf16; Bt: (fo, K) bf16 pre-transposed; Out: (MPAD, ldo) bf16.
// K % 32 == 0. Grid: (MPAD/128, fo/BN). No guards (M padded, rows exact).
// LDS layout is exactly lane order (required by global_load_lds); the 16B seg
// within each 64B row is XOR-swizzled via the GLOBAL address so fragment
// ds_read_b128 spreads 2 lanes/bank (free) instead of 8-way.
template <int BN>
__global__ __launch_bounds__(256) void gemm_mfma(
        const ushort* __restrict__ A, int lda, int K,
        const ushort* __restrict__ Bt,
        const float* __restrict__ bias,
        ushort* __restrict__ Out, int ldo) {
    constexpr int BM = 128, BK = 32;
    constexpr int WR = (BN == 128) ? 2 : 4;   // waves along M
    constexpr int SM = BM / WR;               // 64 or 32
    constexpr int SN = (BN == 128) ? 64 : BN;
    constexpr int FM = SM / 16;
    constexpr int FN = SN / 16;
    constexpr int CB = BN / 16;               // B staging calls (1KB each)
    __shared__ __align__(16) ushort As[BM][BK];
    __shared__ __align__(16) ushort Bs[BN][BK];
    int tid = threadIdx.x;
    int wv = tid >> 6, ln = tid & 63;
    int wm = (BN == 128) ? (wv & 1) : wv;
    int wn = (BN == 128) ? (wv >> 1) : 0;
    int q = ln >> 4, r16 = ln & 15;
    int m0 = blockIdx.x * BM;
    int n0 = blockIdx.y * BN;

    // staging lane geometry: within a 16-row call, lane covers row ln>>2,
    // LDS slot ln&3; global seg fetched = slot ^ ((row>>1)&3)
    int lrow = ln >> 2;
    int gseg = (ln & 3) ^ ((ln >> 3) & 3);
    const ushort* Abase = A + (size_t)(m0 + lrow) * lda + gseg * 8;
    const ushort* Bbase = Bt + (size_t)(n0 + lrow) * K + gseg * 8;

    floatx4 acc[FM][FN];
    #pragma unroll
    for (int i = 0; i < FM; ++i)
        #pragma unroll
        for (int j = 0; j < FN; ++j) acc[i][j] = (floatx4){0.f, 0.f, 0.f, 0.f};

    // fragment LDS offsets (in ushorts): row*BK + swizzled-seg*8
    int sw = (q ^ ((r16 >> 1) & 3)) * 8;
    int aoff[FM], boff[FN];
    #pragma unroll
    for (int i = 0; i < FM; ++i) aoff[i] = (wm * SM + i * 16 + r16) * BK + sw;
    #pragma unroll
    for (int j = 0; j < FN; ++j) boff[j] = (wn * SN + j * 16 + r16) * BK + sw;
    const ushort* ldsA = &As[0][0];
    const ushort* ldsB = &Bs[0][0];

    for (int k0 = 0; k0 < K; k0 += BK) {
        // A tile: 8 calls of 16 rows; wave wv does calls {wv, wv+4}
        gld_lds16(Abase + (size_t)(wv * 16) * lda + k0, &As[wv * 16][0]);
        gld_lds16(Abase + (size_t)(64 + wv * 16) * lda + k0, &As[64 + wv * 16][0]);
        // B tile: CB calls
        if constexpr (CB >= 4) {
            gld_lds16(Bbase + (size_t)(wv * 16) * K + k0, &Bs[wv * 16][0]);
            if constexpr (CB == 8)
                gld_lds16(Bbase + (size_t)(64 + wv * 16) * K + k0, &Bs[64 + wv * 16][0]);
        } else {
            if (wv < CB) gld_lds16(Bbase + (size_t)(wv * 16) * K + k0, &Bs[wv * 16][0]);
        }
        __syncthreads();
        short8 af[FM], bf[FN];
        #pragma unroll
        for (int i = 0; i < FM; ++i) af[i] = *(const short8*)(ldsA + aoff[i]);
        #pragma unroll
        for (int j = 0; j < FN; ++j) bf[j] = *(const short8*)(ldsB + boff[j]);
        #pragma unroll
        for (int i = 0; i < FM; ++i)
            #pragma unroll
            for (int j = 0; j < FN; ++j)
                acc[i][j] = __builtin_amdgcn_mfma_f32_16x16x32_bf16(
                    af[i], bf[j], acc[i][j], 0, 0, 0);
        __syncthreads();
    }
    // epilogue: bias + softplus -> bf16
    #pragma unroll
    for (int i = 0; i < FM; ++i) {
        #pragma unroll
        for (int j = 0; j < FN; ++j) {
            int n = n0 + wn * SN + j * 16 + r16;
            float bv = bias[n];
            #pragma unroll
            for (int r = 0; r < 4; ++r) {
                int m = m0 + wm * SM + i * 16 + q * 4 + r;
                float v = acc[i][j][r] + bv;
                Out[(size_t)m * ldo + n] = f2b(softplus_f(v));
            }
        }
    }
}

// ---------------- final FC: (N,512) bf16 @ (512,3) fp32 + b ----------------
__global__ __launch_bounds__(256) void fc_kernel(
        const ushort* __restrict__ H, const float* __restrict__ Wfc,
        const float* __restrict__ bfc, float* __restrict__ Out, int M) {
    int node = blockIdx.x * 4 + (threadIdx.x >> 6);
    int lane = threadIdx.x & 63;
    if (node >= M) return;
    const ushort* h = H + (size_t)node * 512 + lane * 8;
    ushort4 v0 = *(const ushort4*)h;
    ushort4 v1 = *(const ushort4*)(h + 4);
    ushort vv[8] = {v0.x, v0.y, v0.z, v0.w, v1.x, v1.y, v1.z, v1.w};
    float a0 = 0.f, a1 = 0.f, a2 = 0.f;
    #pragma unroll
    for (int j = 0; j < 8; ++j) {
        float x = b2f(vv[j]);
        int k = lane * 8 + j;
        a0 += x * Wfc[k * 3 + 0];
        a1 += x * Wfc[k * 3 + 1];
        a2 += x * Wfc[k * 3 + 2];
    }
    #pragma unroll
    for (int off = 32; off > 0; off >>= 1) {
        a0 += __shfl_down(a0, off);
        a1 += __shfl_down(a1, off);
        a2 += __shfl_down(a2, off);
    }
    if (lane == 0) {
        Out[node * 3 + 0] = a0 + bfc[0];
        Out[node * 3 + 1] = a1 + bfc[1];
        Out[node * 3 + 2] = a2 + bfc[2];
    }
}

static inline size_t align256(size_t x) { return (x + 255) & ~(size_t)255; }

extern "C" void kernel_launch(void* const* d_in, const int* in_sizes, int n_in,
                              void* d_out, int out_size, void* d_ws, size_t ws_size,
                              hipStream_t stream) {
    const float* x   = (const float*)d_in[0];
    const int*   ei  = (const int*)d_in[1];
    const float* ew  = (const float*)d_in[2];
    const float* W[6]  = { (const float*)d_in[4],  (const float*)d_in[6],
                           (const float*)d_in[8],  (const float*)d_in[10],
                           (const float*)d_in[12], (const float*)d_in[14] };
    const float* Bv[6] = { (const float*)d_in[5],  (const float*)d_in[7],
                           (const float*)d_in[9],  (const float*)d_in[11],
                           (const float*)d_in[13], (const float*)d_in[15] };
    const float* fc_w = (const float*)d_in[16];
    const float* fc_b = (const float*)d_in[17];
    float* out = (float*)d_out;

    const int* e_row = ei;        // edge_index[0]
    const int* e_col = ei + EE;   // edge_index[1]

    const int fi_arr[6]   = { 128, 16, 32, 64, 128, 256 };
    const int fo_arr[6]   = { 16, 32, 64, 128, 256, 512 };
    const int Kpad_arr[6] = { 384, 64, 96, 192, 384, 768 };  // K rounded to 32
    const int ldo_arr[6]  = { 64, 96, 192, 384, 768, 512 };  // next Kpad; L6 plain

    // ---- workspace carve ----
    char* p = (char*)d_ws;
    float* deg    = (float*)p; p += align256((size_t)NN * 4);
    int*   counts = (int*)p;   p += align256((size_t)NN * 4);
    int*   offs   = (int*)p;   p += align256((size_t)(NN + 1) * 4);
    int*   cursor = (int*)p;   p += align256((size_t)NN * 4);
    int*   csr_r  = (int*)p;   p += align256((size_t)EE * 4);
    float* csr_w  = (float*)p; p += align256((size_t)EE * 4);
    ushort* Bt[6];
    for (int L = 0; L < 6; ++L) {
        Bt[L] = (ushort*)p;
        p += align256((size_t)fo_arr[L] * Kpad_arr[L] * 2);
    }
    ushort* buf0 = (ushort*)p; p += align256((size_t)MPAD * 768 * 2);
    ushort* buf1 = (ushort*)p; p += align256((size_t)MPAD * 768 * 2);
    (void)ws_size; (void)n_in; (void)in_sizes; (void)out_size;

    // ---- zero init: only deg/counts. Buffer poison (0xAAAA bf16 = -3e-13,
    // finite) is harmless: pad rows never feed real rows, and K-pad columns
    // multiply zeroed Bt columns.
    hipMemsetAsync(deg, 0, (size_t)NN * 4, stream);
    hipMemsetAsync(counts, 0, (size_t)NN * 4, stream);

    // ---- graph preprocessing ----
    {
        int blocks = (EE + 255) / 256;
        edge_pass1<<<blocks, 256, 0, stream>>>(e_row, e_col, ew, deg, counts, EE);
        scan_kernel<<<1, 1024, 0, stream>>>(counts, offs, cursor, NN);
        edge_pass2<<<blocks, 256, 0, stream>>>(e_row, e_col, ew, deg, cursor, csr_r, csr_w, EE);
    }

    // ---- weights -> bf16 transposed (fo, Kpad), pads zeroed ----
    for (int L = 0; L < 6; ++L) {
        int total = fo_arr[L] * Kpad_arr[L];
        wconv_kernel<<<(total + 255) / 256, 256, 0, stream>>>(
            W[L], Bt[L], 3 * fi_arr[L], Kpad_arr[L], fo_arr[L]);
    }

    // ---- stage x into buf0 cols [0,128), ld=384, bf16 ----
    {
        int total = NN * 128;
        copy_x_kernel<<<(total + 255) / 256, 256, 0, stream>>>(x, buf0, 128, 384, NN);
    }

    ushort* Abuf[6] = { buf0, buf1, buf0, buf1, buf0, buf1 };
    ushort* Obuf[6] = { buf1, buf0, buf1, buf0, buf1, buf0 };

    for (int L = 0; L < 6; ++L) {
        int fi = fi_arr[L], fo = fo_arr[L];
        int ldA = Kpad_arr[L];
        int ldO = ldo_arr[L];
        ushort* A = Abuf[L];
        ushort* O = Obuf[L];

        // two SpMV passes: Tx1 = Lhat@Tx0; Tx2 = 2*Lhat@Tx1 - Tx0
        #define LMV_LAUNCH(FI, NB)                                                     \
            lmv_bf16<FI><<<NB, 256, 0, stream>>>(A, A + fi, nullptr, ldA,              \
                                                 offs, csr_r, csr_w, 1.0f, NN);        \
            lmv_bf16<FI><<<NB, 256, 0, stream>>>(A + fi, A + 2 * fi, A, ldA,           \
                                                 offs, csr_r, csr_w, 2.0f, NN);
        switch (fi) {
            case 16:  { LMV_LAUNCH(16,  (NN + 15) / 16) } break;
            case 32:  { LMV_LAUNCH(32,  (NN + 7) / 8) } break;
            case 64:  { LMV_LAUNCH(64,  (NN + 3) / 4) } break;
            case 128: { LMV_LAUNCH(128, (NN + 3) / 4) } break;
            case 256: { LMV_LAUNCH(256, (NN + 3) / 4) } break;
        }
        #undef LMV_LAUNCH

        // GEMM: Out = softplus([Tx0|Tx1|Tx2] @ W + b)
        int K = Kpad_arr[L];
        switch (fo) {
            case 16:
                gemm_mfma<16><<<dim3(MPAD / 128, 1), 256, 0, stream>>>(
                    A, ldA, K, Bt[L], Bv[L], O, ldO);
                break;
            case 32:
                gemm_mfma<32><<<dim3(MPAD / 128, 1), 256, 0, stream>>>(
                    A, ldA, K, Bt[L], Bv[L], O, ldO);
                break;
            case 64:
                gemm_mfma<64><<<dim3(MPAD / 128, 1), 256, 0, stream>>>(
                    A, ldA, K, Bt[L], Bv[L], O, ldO);
                break;
            default:
                gemm_mfma<128><<<dim3(MPAD / 128, fo / 128), 256, 0, stream>>>(
                    A, ldA, K, Bt[L], Bv[L], O, ldO);
                break;
        }
    }

    // final FC: buf0 (N,512) bf16 @ fc_w (512,3) + fc_b
    fc_kernel<<<(NN + 3) / 4, 256, 0, stream>>>(buf0, fc_w, fc_b, out, NN);
}

// Round 4
// 665.381 us; speedup vs baseline: 2.7987x; 1.1605x over previous
//
#include <hip/hip_runtime.h>
#include <math.h>
#include <stdint.h>

#define NN 30000
#define EE 480000
#define MPAD 30080   // 235 * 128

typedef __attribute__((ext_vector_type(8))) short short8;
typedef __attribute__((ext_vector_type(4))) float floatx4;

// ---------------- bf16 helpers ----------------
__device__ __forceinline__ float b2f(ushort u) {
    union { uint u; float f; } c; c.u = ((uint)u) << 16; return c.f;
}
__device__ __forceinline__ ushort f2b(float f) {
    union { float f; uint u; } c; c.f = f;
    uint u = c.u;
    uint r = (u + 0x7FFFu + ((u >> 16) & 1u)) >> 16;
    return (ushort)r;
}
__device__ __forceinline__ float softplus_f(float x) {
    return fmaxf(x, 0.f) + log1pf(expf(-fabsf(x)));
}

// ---- async global->LDS, 16B per lane. LDS dest = wave-uniform base + lane*16.
__device__ __forceinline__ void gld_lds16(const void* g, void* lds) {
    __builtin_amdgcn_global_load_lds(
        (__attribute__((address_space(1))) void*)(uintptr_t)(g),
        (__attribute__((address_space(3))) void*)(uint32_t)(uintptr_t)(lds),
        16, 0, 0);
}

// ---------------- edge pass 1: degree + col histogram ----------------
__global__ void edge_pass1(const int* __restrict__ row, const int* __restrict__ col,
                           const float* __restrict__ ew,
                           float* __restrict__ deg, int* __restrict__ counts, int E) {
    int e = blockIdx.x * blockDim.x + threadIdx.x;
    if (e >= E) return;
    atomicAdd(&deg[row[e]], ew[e]);
    atomicAdd(&counts[col[e]], 1);
}

// ---------------- single-block exclusive scan over counts ----------------
__global__ void scan_kernel(const int* __restrict__ counts, int* __restrict__ offs,
                            int* __restrict__ cursor, int N) {
    __shared__ int s[1024];
    int t = threadIdx.x;
    int chunk = (N + 1023) / 1024;
    int beg = t * chunk;
    int end = min(beg + chunk, N);
    int sum = 0;
    for (int i = beg; i < end; ++i) sum += counts[i];
    s[t] = sum;
    __syncthreads();
    for (int off = 1; off < 1024; off <<= 1) {
        int v = (t >= off) ? s[t - off] : 0;
        __syncthreads();
        s[t] += v;
        __syncthreads();
    }
    int run = s[t] - sum;
    for (int i = beg; i < end; ++i) {
        offs[i] = run;
        cursor[i] = run;
        run += counts[i];
    }
    if (t == 1023) offs[N] = s[1023];
}

// ---------------- edge pass 2: scatter into CSR-by-col ----------------
__global__ void edge_pass2(const int* __restrict__ row, const int* __restrict__ col,
                           const float* __restrict__ ew, const float* __restrict__ deg,
                           int* __restrict__ cursor,
                           int* __restrict__ csr_row, float* __restrict__ csr_w, int E) {
    int e = blockIdx.x * blockDim.x + threadIdx.x;
    if (e >= E) return;
    int r = row[e];
    float d = deg[r];
    float wv = (d > 0.f) ? (-ew[e] / d) : 0.f;  // -(2/lmax)*deg_inv*ew, lmax=2
    int pos = atomicAdd(&cursor[col[e]], 1);
    csr_row[pos] = r;
    csr_w[pos] = wv;
}

// ---------------- x (fp32) -> dense bf16 (N,128) ----------------
__global__ void copy_x_kernel(const float* __restrict__ x, ushort* __restrict__ out,
                              int total4) {
    int idx = blockIdx.x * blockDim.x + threadIdx.x;
    if (idx >= total4) return;
    float4 v = *(const float4*)(x + idx * 4);
    ushort4 o;
    o.x = f2b(v.x); o.y = f2b(v.y); o.z = f2b(v.z); o.w = f2b(v.w);
    *(ushort4*)(out + idx * 4) = o;
}

// ---------------- weight convert: W (K, fo) fp32 -> Bt (fo, Kpad) bf16 -----
__global__ void wconv_kernel(const float* __restrict__ W, ushort* __restrict__ Bt,
                             int K, int Kpad, int fo) {
    int idx = blockIdx.x * blockDim.x + threadIdx.x;
    int total = fo * Kpad;
    if (idx >= total) return;
    int n = idx / Kpad, k = idx - n * Kpad;
    float v = (k < K) ? W[(size_t)k * fo + n] : 0.f;
    Bt[idx] = f2b(v);
}

// ---- L1 weights: W (3,128,16) fp32 -> Bt1 (48,128) bf16, Bt1[j*16+n][k]=W[j][k][n]
__global__ void wconv1_kernel(const float* __restrict__ W, ushort* __restrict__ Bt) {
    int idx = blockIdx.x * blockDim.x + threadIdx.x;  // 48*128
    if (idx >= 48 * 128) return;
    int row = idx >> 7, k = idx & 127;
    int j = row >> 4, n = row & 15;
    Bt[idx] = f2b(W[(j * 128 + k) * 16 + n]);
}

// ---------------- gather-accumulate helper ----------------
template <int VEC>
__device__ __forceinline__ void gacc(const ushort* __restrict__ p, float w,
                                     float* acc) {
    if constexpr (VEC == 4) {
        ushort4 u = *(const ushort4*)p;
        acc[0] += w * b2f(u.x); acc[1] += w * b2f(u.y);
        acc[2] += w * b2f(u.z); acc[3] += w * b2f(u.w);
    } else if constexpr (VEC == 2) {
        ushort2 u = *(const ushort2*)p;
        acc[0] += w * b2f(u.x); acc[1] += w * b2f(u.y);
    } else {
        acc[0] += w * b2f(*p);
    }
}

// ---------------- SpMV gather (bf16, fp32 accum, 4 MLP chains) -------------
// Out[n,:] = scale * sum_e w[e]*A[rows[e],:] - (Sub ? Sub[n,:] : 0)
template <int FI>
__global__ __launch_bounds__(256) void lmv_bf16(
        const ushort* __restrict__ A, ushort* __restrict__ Out,
        const ushort* __restrict__ Sub, int ldi, int ldo,
        const int* __restrict__ offs, const int* __restrict__ rows,
        const float* __restrict__ w, float scale, int N) {
    constexpr int NPW = (FI >= 64) ? 1 : (64 / FI);
    constexpr int VEC = (FI >= 64) ? (FI / 64) : 1;
    int wave = threadIdx.x >> 6;
    int lane = threadIdx.x & 63;
    int sub = (NPW == 1) ? 0 : (lane / FI);
    int fbase = (NPW == 1) ? lane * VEC : (lane & (FI - 1));
    int node = blockIdx.x * (4 * NPW) + wave * NPW + sub;
    if (node >= N) return;
    int e0 = offs[node], e1 = offs[node + 1];
    float acc[4][VEC];
    #pragma unroll
    for (int c = 0; c < 4; ++c)
        #pragma unroll
        for (int v = 0; v < VEC; ++v) acc[c][v] = 0.f;
    int e = e0;
    for (; e + 4 <= e1; e += 4) {
        int r0 = rows[e], r1 = rows[e + 1], r2 = rows[e + 2], r3 = rows[e + 3];
        float w0 = w[e], w1 = w[e + 1], w2 = w[e + 2], w3 = w[e + 3];
        gacc<VEC>(A + (size_t)r0 * ldi + fbase, w0, acc[0]);
        gacc<VEC>(A + (size_t)r1 * ldi + fbase, w1, acc[1]);
        gacc<VEC>(A + (size_t)r2 * ldi + fbase, w2, acc[2]);
        gacc<VEC>(A + (size_t)r3 * ldi + fbase, w3, acc[3]);
    }
    for (; e < e1; ++e) {
        gacc<VEC>(A + (size_t)rows[e] * ldi + fbase, w[e], acc[0]);
    }
    #pragma unroll
    for (int v = 0; v < VEC; ++v)
        acc[0][v] = (acc[0][v] + acc[1][v]) + (acc[2][v] + acc[3][v]);
    ushort* o = Out + (size_t)node * ldo + fbase;
    if (Sub) {
        const ushort* s = Sub + (size_t)node * ldo + fbase;
        #pragma unroll
        for (int v = 0; v < VEC; ++v) o[v] = f2b(scale * acc[0][v] - b2f(s[v]));
    } else {
        #pragma unroll
        for (int v = 0; v < VEC; ++v) o[v] = f2b(scale * acc[0][v]);
    }
}

// ---------------- L1 combine: h1 = softplus(Y0 + Z1 + 2*Z3 - Y2 + b) -------
__global__ __launch_bounds__(256) void combine_l1(
        const ushort* __restrict__ Y, const ushort* __restrict__ Z,
        const ushort* __restrict__ Z3, const float* __restrict__ b,
        ushort* __restrict__ Out, int N) {
    int idx = blockIdx.x * blockDim.x + threadIdx.x;
    if (idx >= N * 16) return;
    int n = idx >> 4, f = idx & 15;
    float y0 = b2f(Y[n * 48 + f]);
    float y2 = b2f(Y[n * 48 + 32 + f]);
    float z1 = b2f(Z[n * 32 + f]);
    float z3 = b2f(Z3[n * 16 + f]);
    float v = y0 + z1 + 2.f * z3 - y2 + b[f];
    Out[(size_t)n * 64 + f] = f2b(softplus_f(v));
}

// ---------------- MFMA GEMM, global_load_lds staging ----------------
// A: (MPAD, lda) bf16; Bt: (BN_total, K) bf16 pre-transposed; Out bf16.
// ACT: bias+softplus epilogue; else raw store. No guards (M padded).
template <int BN, bool ACT = true>
__global__ __launch_bounds__(256) void gemm_mfma(
        const ushort* __restrict__ A, int lda, int K,
        const ushort* __restrict__ Bt,
        const float* __restrict__ bias,
        ushort* __restrict__ Out, int ldo) {
    constexpr int BM = 128, BK = 32;
    constexpr int WR = (BN == 128) ? 2 : 4;   // waves along M
    constexpr int SM = BM / WR;               // 64 or 32
    constexpr int SN = (BN == 128) ? 64 : BN;
    constexpr int FM = SM / 16;
    constexpr int FN = SN / 16;
    constexpr int CB = BN / 16;               // B staging calls (1KB each)
    __shared__ __align__(16) ushort As[BM][BK];
    __shared__ __align__(16) ushort Bs[BN][BK];
    int tid = threadIdx.x;
    int wv = tid >> 6, ln = tid & 63;
    int wm = (BN == 128) ? (wv & 1) : wv;
    int wn = (BN == 128) ? (wv >> 1) : 0;
    int q = ln >> 4, r16 = ln & 15;
    int m0 = blockIdx.x * BM;
    int n0 = blockIdx.y * BN;

    // staging lane geometry: lane covers row ln>>2, LDS slot ln&3;
    // global seg fetched = slot ^ ((row>>1)&3) (bank-spread swizzle)
    int lrow = ln >> 2;
    int gseg = (ln & 3) ^ ((ln >> 3) & 3);
    const ushort* Abase = A + (size_t)(m0 + lrow) * lda + gseg * 8;
    const ushort* Bbase = Bt + (size_t)(n0 + lrow) * K + gseg * 8;

    floatx4 acc[FM][FN];
    #pragma unroll
    for (int i = 0; i < FM; ++i)
        #pragma unroll
        for (int j = 0; j < FN; ++j) acc[i][j] = (floatx4){0.f, 0.f, 0.f, 0.f};

    // fragment LDS offsets (ushorts): row*BK + swizzled-seg*8
    int sw = (q ^ ((r16 >> 1) & 3)) * 8;
    int aoff[FM], boff[FN];
    #pragma unroll
    for (int i = 0; i < FM; ++i) aoff[i] = (wm * SM + i * 16 + r16) * BK + sw;
    #pragma unroll
    for (int j = 0; j < FN; ++j) boff[j] = (wn * SN + j * 16 + r16) * BK + sw;
    const ushort* ldsA = &As[0][0];
    const ushort* ldsB = &Bs[0][0];

    for (int k0 = 0; k0 < K; k0 += BK) {
        gld_lds16(Abase + (size_t)(wv * 16) * lda + k0, &As[wv * 16][0]);
        gld_lds16(Abase + (size_t)(64 + wv * 16) * lda + k0, &As[64 + wv * 16][0]);
        if constexpr (CB >= 4) {
            gld_lds16(Bbase + (size_t)(wv * 16) * K + k0, &Bs[wv * 16][0]);
            if constexpr (CB == 8)
                gld_lds16(Bbase + (size_t)(64 + wv * 16) * K + k0, &Bs[64 + wv * 16][0]);
        } else {
            if (wv < CB) gld_lds16(Bbase + (size_t)(wv * 16) * K + k0, &Bs[wv * 16][0]);
        }
        __syncthreads();
        short8 af[FM], bf[FN];
        #pragma unroll
        for (int i = 0; i < FM; ++i) af[i] = *(const short8*)(ldsA + aoff[i]);
        #pragma unroll
        for (int j = 0; j < FN; ++j) bf[j] = *(const short8*)(ldsB + boff[j]);
        #pragma unroll
        for (int i = 0; i < FM; ++i)
            #pragma unroll
            for (int j = 0; j < FN; ++j)
                acc[i][j] = __builtin_amdgcn_mfma_f32_16x16x32_bf16(
                    af[i], bf[j], acc[i][j], 0, 0, 0);
        __syncthreads();
    }
    #pragma unroll
    for (int i = 0; i < FM; ++i) {
        #pragma unroll
        for (int j = 0; j < FN; ++j) {
            int n = n0 + wn * SN + j * 16 + r16;
            float bv = ACT ? bias[n] : 0.f;
            #pragma unroll
            for (int r = 0; r < 4; ++r) {
                int m = m0 + wm * SM + i * 16 + q * 4 + r;
                float v = acc[i][j][r] + bv;
                Out[(size_t)m * ldo + n] = f2b(ACT ? softplus_f(v) : v);
            }
        }
    }
}

// ---------------- final FC: (N,512) bf16 @ (512,3) fp32 + b ----------------
__global__ __launch_bounds__(256) void fc_kernel(
        const ushort* __restrict__ H, const float* __restrict__ Wfc,
        const float* __restrict__ bfc, float* __restrict__ Out, int M) {
    int node = blockIdx.x * 4 + (threadIdx.x >> 6);
    int lane = threadIdx.x & 63;
    if (node >= M) return;
    const ushort* h = H + (size_t)node * 512 + lane * 8;
    ushort4 v0 = *(const ushort4*)h;
    ushort4 v1 = *(const ushort4*)(h + 4);
    ushort vv[8] = {v0.x, v0.y, v0.z, v0.w, v1.x, v1.y, v1.z, v1.w};
    float a0 = 0.f, a1 = 0.f, a2 = 0.f;
    #pragma unroll
    for (int j = 0; j < 8; ++j) {
        float x = b2f(vv[j]);
        int k = lane * 8 + j;
        a0 += x * Wfc[k * 3 + 0];
        a1 += x * Wfc[k * 3 + 1];
        a2 += x * Wfc[k * 3 + 2];
    }
    #pragma unroll
    for (int off = 32; off > 0; off >>= 1) {
        a0 += __shfl_down(a0, off);
        a1 += __shfl_down(a1, off);
        a2 += __shfl_down(a2, off);
    }
    if (lane == 0) {
        Out[node * 3 + 0] = a0 + bfc[0];
        Out[node * 3 + 1] = a1 + bfc[1];
        Out[node * 3 + 2] = a2 + bfc[2];
    }
}

static inline size_t align256(size_t x) { return (x + 255) & ~(size_t)255; }

extern "C" void kernel_launch(void* const* d_in, const int* in_sizes, int n_in,
                              void* d_out, int out_size, void* d_ws, size_t ws_size,
                              hipStream_t stream) {
    const float* x   = (const float*)d_in[0];
    const int*   ei  = (const int*)d_in[1];
    const float* ew  = (const float*)d_in[2];
    const float* W[6]  = { (const float*)d_in[4],  (const float*)d_in[6],
                           (const float*)d_in[8],  (const float*)d_in[10],
                           (const float*)d_in[12], (const float*)d_in[14] };
    const float* Bv[6] = { (const float*)d_in[5],  (const float*)d_in[7],
                           (const float*)d_in[9],  (const float*)d_in[11],
                           (const float*)d_in[13], (const float*)d_in[15] };
    const float* fc_w = (const float*)d_in[16];
    const float* fc_b = (const float*)d_in[17];
    float* out = (float*)d_out;

    const int* e_row = ei;        // edge_index[0]
    const int* e_col = ei + EE;   // edge_index[1]

    // layers 2..6 (index 1..5)
    const int fi_arr[5]   = { 16, 32, 64, 128, 256 };
    const int fo_arr[5]   = { 32, 64, 128, 256, 512 };
    const int Kpad_arr[5] = { 64, 96, 192, 384, 768 };
    const int ldo_arr[5]  = { 96, 192, 384, 768, 512 };

    // ---- workspace carve ----
    char* p = (char*)d_ws;
    float* deg    = (float*)p; p += align256((size_t)NN * 4);
    int*   counts = (int*)p;   p += align256((size_t)NN * 4);
    int*   offs   = (int*)p;   p += align256((size_t)(NN + 1) * 4);
    int*   cursor = (int*)p;   p += align256((size_t)NN * 4);
    int*   csr_r  = (int*)p;   p += align256((size_t)EE * 4);
    float* csr_w  = (float*)p; p += align256((size_t)EE * 4);
    ushort* Bt1   = (ushort*)p; p += align256((size_t)48 * 128 * 2);
    ushort* Bt[5];
    for (int L = 0; L < 5; ++L) {
        Bt[L] = (ushort*)p;
        p += align256((size_t)fo_arr[L] * Kpad_arr[L] * 2);
    }
    ushort* xb   = (ushort*)p; p += align256((size_t)MPAD * 128 * 2);
    ushort* Ybuf = (ushort*)p; p += align256((size_t)MPAD * 48 * 2);
    ushort* Zbuf = (ushort*)p; p += align256((size_t)MPAD * 32 * 2);
    ushort* Z3b  = (ushort*)p; p += align256((size_t)MPAD * 16 * 2);
    ushort* buf0 = (ushort*)p; p += align256((size_t)MPAD * 768 * 2);
    ushort* buf1 = (ushort*)p; p += align256((size_t)MPAD * 768 * 2);
    (void)ws_size; (void)n_in; (void)in_sizes; (void)out_size;

    // ---- zero init: only deg/counts (buffer poison harmless: pad rows never
    // feed real rows; K-pad cols multiply zeroed Bt cols) ----
    hipMemsetAsync(deg, 0, (size_t)NN * 4, stream);
    hipMemsetAsync(counts, 0, (size_t)NN * 4, stream);

    // ---- graph preprocessing ----
    {
        int blocks = (EE + 255) / 256;
        edge_pass1<<<blocks, 256, 0, stream>>>(e_row, e_col, ew, deg, counts, EE);
        scan_kernel<<<1, 1024, 0, stream>>>(counts, offs, cursor, NN);
        edge_pass2<<<blocks, 256, 0, stream>>>(e_row, e_col, ew, deg, cursor, csr_r, csr_w, EE);
    }

    // ---- weights -> bf16 transposed ----
    wconv1_kernel<<<(48 * 128 + 255) / 256, 256, 0, stream>>>(W[0], Bt1);
    for (int L = 0; L < 5; ++L) {
        int total = fo_arr[L] * Kpad_arr[L];
        wconv_kernel<<<(total + 255) / 256, 256, 0, stream>>>(
            W[L + 1], Bt[L], 3 * fi_arr[L], Kpad_arr[L], fo_arr[L]);
    }

    // ---- x -> bf16 dense (N,128) ----
    copy_x_kernel<<<(NN * 128 / 4 + 255) / 256, 256, 0, stream>>>(x, xb, NN * 128 / 4);

    // ---- Layer 1 in output space: Y = x @ [W0|W1|W2]  (30080 x 48, K=128) --
    gemm_mfma<48, false><<<dim3(MPAD / 128, 1), 256, 0, stream>>>(
        xb, 128, 128, Bt1, nullptr, Ybuf, 48);
    // Z = Lhat @ [Y1|Y2]  (32-wide)
    lmv_bf16<32><<<(NN + 7) / 8, 256, 0, stream>>>(
        Ybuf + 16, Zbuf, nullptr, 48, 32, offs, csr_r, csr_w, 1.0f, NN);
    // Z3 = Lhat @ Z2  (16-wide)
    lmv_bf16<16><<<(NN + 15) / 16, 256, 0, stream>>>(
        Zbuf + 16, Z3b, nullptr, 32, 16, offs, csr_r, csr_w, 1.0f, NN);
    // h1 = softplus(Y0 + Z1 + 2*Z3 - Y2 + b1) -> buf1 cols[0,16), ld=64
    combine_l1<<<(NN * 16 + 255) / 256, 256, 0, stream>>>(
        Ybuf, Zbuf, Z3b, Bv[0], buf1, NN);

    // ---- Layers 2..6 ----
    ushort* Abuf[5] = { buf1, buf0, buf1, buf0, buf1 };
    ushort* Obuf[5] = { buf0, buf1, buf0, buf1, buf0 };

    for (int L = 0; L < 5; ++L) {
        int fi = fi_arr[L], fo = fo_arr[L];
        int ldA = Kpad_arr[L];
        int ldO = ldo_arr[L];
        ushort* A = Abuf[L];
        ushort* O = Obuf[L];

        #define LMV_LAUNCH(FI, NB)                                                    \
            lmv_bf16<FI><<<NB, 256, 0, stream>>>(A, A + fi, nullptr, ldA, ldA,        \
                                                 offs, csr_r, csr_w, 1.0f, NN);       \
            lmv_bf16<FI><<<NB, 256, 0, stream>>>(A + fi, A + 2 * fi, A, ldA, ldA,     \
                                                 offs, csr_r, csr_w, 2.0f, NN);
        switch (fi) {
            case 16:  { LMV_LAUNCH(16,  (NN + 15) / 16) } break;
            case 32:  { LMV_LAUNCH(32,  (NN + 7) / 8) } break;
            case 64:  { LMV_LAUNCH(64,  (NN + 3) / 4) } break;
            case 128: { LMV_LAUNCH(128, (NN + 3) / 4) } break;
            case 256: { LMV_LAUNCH(256, (NN + 3) / 4) } break;
        }
        #undef LMV_LAUNCH

        int K = Kpad_arr[L];
        switch (fo) {
            case 32:
                gemm_mfma<32><<<dim3(MPAD / 128, 1), 256, 0, stream>>>(
                    A, ldA, K, Bt[L], Bv[L + 1], O, ldO);
                break;
            case 64:
                gemm_mfma<64><<<dim3(MPAD / 128, 1), 256, 0, stream>>>(
                    A, ldA, K, Bt[L], Bv[L + 1], O, ldO);
                break;
            default:
                gemm_mfma<128><<<dim3(MPAD / 128, fo / 128), 256, 0, stream>>>(
                    A, ldA, K, Bt[L], Bv[L + 1], O, ldO);
                break;
        }
    }

    // final FC: buf0 (N,512) bf16 @ fc_w (512,3) + fc_b
    fc_kernel<<<(NN + 3) / 4, 256, 0, stream>>>(buf0, fc_w, fc_b, out, NN);
}